// Round 1
// baseline (1073.697 us; speedup 1.0000x reference)
//
#include <hip/hip_runtime.h>
#include <math.h>

#define N_NODES 50000
#define N_EDGES 1600000
#define C 64
#define OUTC 7

// out[r][c] = sum_k x[r][k] * W[c][k]   (W row-major [64][64])
// One wave per row; lane = output channel; x row broadcast via shfl.
__global__ __launch_bounds__(256) void linear64(const float* __restrict__ x,
                                                const float* __restrict__ W,
                                                float* __restrict__ out,
                                                int n_rows) {
    __shared__ float Wt[64 * 65];  // Wt[k*65 + c] = W[c][k]; pad 65 -> conflict-free
    for (int i = threadIdx.x; i < 64 * 64; i += 256) {
        int c = i >> 6, k = i & 63;
        Wt[k * 65 + c] = W[i];
    }
    __syncthreads();
    const int lane = threadIdx.x & 63;
    const int wid  = threadIdx.x >> 6;  // 0..3
    const int RPB  = 64;                // rows per block
    int row0 = blockIdx.x * RPB;
    int rend = row0 + RPB; if (rend > n_rows) rend = n_rows;
    for (int r = row0 + wid; r < rend; r += 4) {
        float xv = x[r * 64 + lane];   // coalesced; lane k holds x[r][k]
        float sum = 0.f;
#pragma unroll
        for (int k = 0; k < 64; ++k) {
            float xk = __shfl(xv, k, 64);
            sum += xk * Wt[k * 65 + lane];
        }
        out[r * 64 + lane] = sum;
    }
}

// agg[dst[e]][c] += t[src[e]][c], one wave per edge, lane = channel
__global__ __launch_bounds__(256) void scatter64(const int* __restrict__ src,
                                                 const int* __restrict__ dst,
                                                 const float* __restrict__ t,
                                                 float* __restrict__ agg) {
    int e = blockIdx.x * 4 + (threadIdx.x >> 6);
    if (e >= N_EDGES) return;
    int lane = threadIdx.x & 63;
    int s = src[e], d = dst[e];
    atomicAdd(&agg[d * 64 + lane], t[s * 64 + lane]);
}

__global__ __launch_bounds__(256) void bias_relu(float* __restrict__ h,
                                                 const float* __restrict__ b,
                                                 int n) {
    int i = blockIdx.x * 256 + threadIdx.x;
    if (i < n) {
        float v = h[i] + b[i & 63];
        h[i] = v > 0.f ? v : 0.f;
    }
}

// out[r][c] = sum_k x[r][k] * W3[c][k], c in [0,7)
__global__ __launch_bounds__(256) void linear7(const float* __restrict__ x,
                                               const float* __restrict__ W,
                                               float* __restrict__ out,
                                               int n_rows) {
    __shared__ float Ws[7 * 64];
    for (int i = threadIdx.x; i < 7 * 64; i += 256) Ws[i] = W[i];
    __syncthreads();
    const int lane = threadIdx.x & 63;
    const int wid  = threadIdx.x >> 6;
    const int cl   = lane < 7 ? lane : 0;  // clamp so all lanes stay in-bounds
    const int RPB  = 64;
    int row0 = blockIdx.x * RPB;
    int rend = row0 + RPB; if (rend > n_rows) rend = n_rows;
    for (int r = row0 + wid; r < rend; r += 4) {
        float xv = x[r * 64 + lane];
        float sum = 0.f;
#pragma unroll
        for (int k = 0; k < 64; ++k) {
            float xk = __shfl(xv, k, 64);  // all lanes shuffle (no divergence here)
            sum += xk * Ws[cl * 64 + k];
        }
        if (lane < 7) out[r * 7 + lane] = sum;
    }
}

// agg[dst[e]][c] += t[src[e]][c], 8 threads per edge (c = tid&7, 7 active)
__global__ __launch_bounds__(256) void scatter7(const int* __restrict__ src,
                                                const int* __restrict__ dst,
                                                const float* __restrict__ t,
                                                float* __restrict__ agg) {
    int idx = blockIdx.x * 256 + threadIdx.x;
    int e = idx >> 3, c = idx & 7;
    if (e >= N_EDGES || c >= 7) return;
    atomicAdd(&agg[dst[e] * 7 + c], t[src[e] * 7 + c]);
}

// in-place: out[i][:] = (z + b3) - logsumexp(z + b3)
__global__ __launch_bounds__(256) void lsm_inplace(float* __restrict__ out,
                                                   const float* __restrict__ b,
                                                   int n_rows) {
    int i = blockIdx.x * 256 + threadIdx.x;
    if (i >= n_rows) return;
    float z[7];
    float m = -1e30f;
#pragma unroll
    for (int c = 0; c < 7; ++c) {
        z[c] = out[i * 7 + c] + b[c];
        m = fmaxf(m, z[c]);
    }
    float s = 0.f;
#pragma unroll
    for (int c = 0; c < 7; ++c) s += __expf(z[c] - m);
    float l = m + __logf(s);
#pragma unroll
    for (int c = 0; c < 7; ++c) out[i * 7 + c] = z[c] - l;
}

extern "C" void kernel_launch(void* const* d_in, const int* in_sizes, int n_in,
                              void* d_out, int out_size, void* d_ws, size_t ws_size,
                              hipStream_t stream) {
    const float* x  = (const float*)d_in[0];
    const int*   ei = (const int*)d_in[1];
    const float* W1 = (const float*)d_in[2];
    const float* b1 = (const float*)d_in[3];
    const float* W2 = (const float*)d_in[4];
    const float* b2 = (const float*)d_in[5];
    const float* W3 = (const float*)d_in[6];
    const float* b3 = (const float*)d_in[7];
    float* out = (float*)d_out;

    const int* src = ei;
    const int* dst = ei + N_EDGES;

    float* t   = (float*)d_ws;            // [N_NODES * 64]  12.8 MB
    float* agg = t + (size_t)N_NODES * C; // [N_NODES * 64]  12.8 MB

    const size_t feat_bytes = (size_t)N_NODES * C * sizeof(float);
    const int lin_grid  = (N_NODES + 63) / 64;
    const int scat_grid = (N_EDGES + 3) / 4;
    const int ew_grid   = ((size_t)N_NODES * C + 255) / 256;

    // ---- layer 1: t = x @ W1^T ; agg = scatter(t) ; h1 = relu(agg + b1)
    linear64<<<lin_grid, 256, 0, stream>>>(x, W1, t, N_NODES);
    hipMemsetAsync(agg, 0, feat_bytes, stream);
    scatter64<<<scat_grid, 256, 0, stream>>>(src, dst, t, agg);
    bias_relu<<<ew_grid, 256, 0, stream>>>(agg, b1, N_NODES * C);

    // ---- layer 2: t = h1 @ W2^T ; agg = scatter(t) ; h2 = relu(agg + b2)
    linear64<<<lin_grid, 256, 0, stream>>>(agg, W2, t, N_NODES);
    hipMemsetAsync(agg, 0, feat_bytes, stream);  // safe: linear64 finished reading h1
    // NOTE: agg was input to linear64 above; stream ordering makes the memset safe.
    scatter64<<<scat_grid, 256, 0, stream>>>(src, dst, t, agg);
    bias_relu<<<ew_grid, 256, 0, stream>>>(agg, b2, N_NODES * C);

    // ---- layer 3: t3 = h2 @ W3^T ; d_out = scatter7(t3) ; log_softmax in place
    float* t3 = t;  // reuse t buffer (only 50000*7 floats needed)
    linear7<<<lin_grid, 256, 0, stream>>>(agg, W3, t3, N_NODES);
    hipMemsetAsync(out, 0, (size_t)N_NODES * OUTC * sizeof(float), stream);
    scatter7<<<(N_EDGES * 8 + 255) / 256, 256, 0, stream>>>(src, dst, t3, out);
    lsm_inplace<<<(N_NODES + 255) / 256, 256, 0, stream>>>(out, b3, N_NODES);
}

// Round 2
// 677.253 us; speedup vs baseline: 1.5854x; 1.5854x over previous
//
#include <hip/hip_runtime.h>
#include <math.h>

#define N_NODES 50000
#define N_EDGES 1600000
#define C 64
#define OUTC 7

// ---------------- CSR build ----------------

__global__ __launch_bounds__(256) void hist_kernel(const int* __restrict__ dst,
                                                   int* __restrict__ deg) {
    int e = blockIdx.x * 256 + threadIdx.x;
    if (e < N_EDGES) atomicAdd(&deg[dst[e]], 1);
}

// Single-block exclusive scan of deg[0..N_NODES) -> off[0..N_NODES]
__global__ __launch_bounds__(1024) void exscan_kernel(const int* __restrict__ deg,
                                                      int* __restrict__ off) {
    __shared__ int part[1024];
    const int tid = threadIdx.x;
    const int CH = (N_NODES + 1023) / 1024;  // 49
    const int base = tid * CH;
    int s = 0;
    for (int i = 0; i < CH; ++i) {
        int idx = base + i;
        if (idx < N_NODES) s += deg[idx];
    }
    part[tid] = s;
    __syncthreads();
    // Hillis-Steele inclusive scan over 1024 partials
    for (int d = 1; d < 1024; d <<= 1) {
        int v = (tid >= d) ? part[tid - d] : 0;
        __syncthreads();
        part[tid] += v;
        __syncthreads();
    }
    int run = (tid == 0) ? 0 : part[tid - 1];
    for (int i = 0; i < CH; ++i) {
        int idx = base + i;
        if (idx < N_NODES) {
            off[idx] = run;
            run += deg[idx];
        }
    }
    if (tid == 1023) off[N_NODES] = part[1023];
}

// csr_src[pos] = src[e], bucketed by dst via atomic cursor
__global__ __launch_bounds__(256) void fill_kernel(const int* __restrict__ src,
                                                   const int* __restrict__ dst,
                                                   int* __restrict__ cursor,
                                                   int* __restrict__ csr_src) {
    int e = blockIdx.x * 256 + threadIdx.x;
    if (e < N_EDGES) {
        int p = atomicAdd(&cursor[dst[e]], 1);
        csr_src[p] = src[e];
    }
}

// ---------------- dense linears ----------------

// out[r][c] = sum_k x[r][k] * W[c][k]   (W row-major [64][64])
__global__ __launch_bounds__(256) void linear64(const float* __restrict__ x,
                                                const float* __restrict__ W,
                                                float* __restrict__ out,
                                                int n_rows) {
    __shared__ float Wt[64 * 65];  // Wt[k*65 + c] = W[c][k]
    for (int i = threadIdx.x; i < 64 * 64; i += 256) {
        int c = i >> 6, k = i & 63;
        Wt[k * 65 + c] = W[i];
    }
    __syncthreads();
    const int lane = threadIdx.x & 63;
    const int wid  = threadIdx.x >> 6;
    int row0 = blockIdx.x * 64;
    int rend = row0 + 64; if (rend > n_rows) rend = n_rows;
    for (int r = row0 + wid; r < rend; r += 4) {
        float xv = x[(size_t)r * 64 + lane];
        float sum = 0.f;
#pragma unroll
        for (int k = 0; k < 64; ++k) {
            float xk = __shfl(xv, k, 64);
            sum += xk * Wt[k * 65 + lane];
        }
        out[(size_t)r * 64 + lane] = sum;
    }
}

// out[r][0..7] padded stride 8: out[r*8+c] = sum_k x[r][k]*W3[c][k] (c<7), 0 at c=7
__global__ __launch_bounds__(256) void linear7(const float* __restrict__ x,
                                               const float* __restrict__ W,
                                               float* __restrict__ out,
                                               int n_rows) {
    __shared__ float Ws[7 * 64];
    for (int i = threadIdx.x; i < 7 * 64; i += 256) Ws[i] = W[i];
    __syncthreads();
    const int lane = threadIdx.x & 63;
    const int wid  = threadIdx.x >> 6;
    const int cl   = lane < 7 ? lane : 0;
    int row0 = blockIdx.x * 64;
    int rend = row0 + 64; if (rend > n_rows) rend = n_rows;
    for (int r = row0 + wid; r < rend; r += 4) {
        float xv = x[(size_t)r * 64 + lane];
        float sum = 0.f;
#pragma unroll
        for (int k = 0; k < 64; ++k) {
            float xk = __shfl(xv, k, 64);
            sum += xk * Ws[cl * 64 + k];
        }
        if (lane < 8) out[(size_t)r * 8 + lane] = (lane < 7) ? sum : 0.f;
    }
}

// ---------------- gather aggregation ----------------

// out[n][c] = act( sum_{e in csr[n]} t[src(e)][c] + b[c] ), one wave per node
__global__ __launch_bounds__(256) void gather64(const int* __restrict__ off,
                                                const int* __restrict__ csr_src,
                                                const float* __restrict__ t,
                                                const float* __restrict__ b,
                                                float* __restrict__ out,
                                                int do_relu) {
    int node = blockIdx.x * 4 + (threadIdx.x >> 6);
    if (node >= N_NODES) return;
    const int lane = threadIdx.x & 63;
    int e0 = off[node], e1 = off[node + 1];
    float sum = 0.f;
    int e = e0;
    for (; e + 3 < e1; e += 4) {
        int s0 = csr_src[e];
        int s1 = csr_src[e + 1];
        int s2 = csr_src[e + 2];
        int s3 = csr_src[e + 3];
        float v0 = t[(size_t)s0 * 64 + lane];
        float v1 = t[(size_t)s1 * 64 + lane];
        float v2 = t[(size_t)s2 * 64 + lane];
        float v3 = t[(size_t)s3 * 64 + lane];
        sum += v0 + v1 + v2 + v3;
    }
    for (; e < e1; ++e) {
        int s = csr_src[e];
        sum += t[(size_t)s * 64 + lane];
    }
    float v = sum + b[lane];
    if (do_relu) v = fmaxf(v, 0.f);
    out[(size_t)node * 64 + lane] = v;
}

// 7-channel gather from stride-8 padded t3: wave processes one node,
// 8 edge-slots x 8 channel-lanes, butterfly-reduce over edge slots.
__global__ __launch_bounds__(256) void gather7(const int* __restrict__ off,
                                               const int* __restrict__ csr_src,
                                               const float* __restrict__ t3,
                                               const float* __restrict__ b,
                                               float* __restrict__ out) {
    int node = blockIdx.x * 4 + (threadIdx.x >> 6);
    if (node >= N_NODES) return;
    const int lane = threadIdx.x & 63;
    const int sub = lane >> 3;  // edge slot 0..7
    const int ch  = lane & 7;   // channel 0..7 (7 is pad)
    int e0 = off[node], e1 = off[node + 1];
    float sum = 0.f;
    for (int e = e0 + sub; e < e1; e += 8) {
        int s = csr_src[e];
        sum += t3[(size_t)s * 8 + ch];
    }
    // reduce across the 8 edge slots (lane bits 3..5); channel bits preserved
    sum += __shfl_xor(sum, 8, 64);
    sum += __shfl_xor(sum, 16, 64);
    sum += __shfl_xor(sum, 32, 64);
    if (lane < 7) out[(size_t)node * 7 + lane] = sum + b[lane];
}

// in-place log_softmax over 7 channels (bias already applied)
__global__ __launch_bounds__(256) void lsm_inplace(float* __restrict__ out,
                                                   int n_rows) {
    int i = blockIdx.x * 256 + threadIdx.x;
    if (i >= n_rows) return;
    float z[7];
    float m = -1e30f;
#pragma unroll
    for (int c = 0; c < 7; ++c) {
        z[c] = out[i * 7 + c];
        m = fmaxf(m, z[c]);
    }
    float s = 0.f;
#pragma unroll
    for (int c = 0; c < 7; ++c) s += __expf(z[c] - m);
    float l = m + __logf(s);
#pragma unroll
    for (int c = 0; c < 7; ++c) out[i * 7 + c] = z[c] - l;
}

extern "C" void kernel_launch(void* const* d_in, const int* in_sizes, int n_in,
                              void* d_out, int out_size, void* d_ws, size_t ws_size,
                              hipStream_t stream) {
    const float* x  = (const float*)d_in[0];
    const int*   ei = (const int*)d_in[1];
    const float* W1 = (const float*)d_in[2];
    const float* b1 = (const float*)d_in[3];
    const float* W2 = (const float*)d_in[4];
    const float* b2 = (const float*)d_in[5];
    const float* W3 = (const float*)d_in[6];
    const float* b3 = (const float*)d_in[7];
    float* out = (float*)d_out;

    const int* src = ei;
    const int* dst = ei + N_EDGES;

    // workspace layout
    float* A   = (float*)d_ws;                    // 50000*64 f32 (t buffer)
    float* B   = A + (size_t)N_NODES * C;         // 50000*64 f32 (h buffer)
    int* off    = (int*)(B + (size_t)N_NODES * C); // 50001
    int* deg    = off + N_NODES + 4;               // 50000
    int* cursor = deg + N_NODES;                   // 50000
    int* csr    = cursor + N_NODES;                // 1.6M

    const int egrid   = (N_EDGES + 255) / 256;
    const int lingrid = (N_NODES + 63) / 64;
    const int ngrid   = (N_NODES + 3) / 4;

    // ---- CSR build (overlaps nothing; needed before first gather)
    hipMemsetAsync(deg, 0, N_NODES * sizeof(int), stream);
    hist_kernel<<<egrid, 256, 0, stream>>>(dst, deg);
    exscan_kernel<<<1, 1024, 0, stream>>>(deg, off);
    hipMemcpyAsync(cursor, off, N_NODES * sizeof(int),
                   hipMemcpyDeviceToDevice, stream);
    fill_kernel<<<egrid, 256, 0, stream>>>(src, dst, cursor, csr);

    // ---- layer 1
    linear64<<<lingrid, 256, 0, stream>>>(x, W1, A, N_NODES);
    gather64<<<ngrid, 256, 0, stream>>>(off, csr, A, b1, B, 1);

    // ---- layer 2
    linear64<<<lingrid, 256, 0, stream>>>(B, W2, A, N_NODES);
    gather64<<<ngrid, 256, 0, stream>>>(off, csr, A, b2, B, 1);

    // ---- layer 3 (7 channels, padded to stride 8 in A)
    linear7<<<lingrid, 256, 0, stream>>>(B, W3, A, N_NODES);
    gather7<<<ngrid, 256, 0, stream>>>(off, csr, A, b3, out);
    lsm_inplace<<<(N_NODES + 255) / 256, 256, 0, stream>>>(out, N_NODES);
}

// Round 3
// 432.403 us; speedup vs baseline: 2.4831x; 1.5663x over previous
//
#include <hip/hip_runtime.h>
#include <math.h>

#define N_NODES 50000
#define N_EDGES 1600000
#define C 64
#define OUTC 7

#define NB 49          // coarse buckets: dst >> 10, dst < 50000 -> 0..48
#define BCAP 40960     // bucket capacity (expected 32768, 6-sigma ~ 33.9k)
#define CHUNK 4096     // edges per phase-1 workgroup

// ---------------- CSR build, phase 1: coarse binning ----------------
// Pack edge as (dst<<16)|src  (both < 50000 < 65536). bucket = v >> 26.
__global__ __launch_bounds__(256) void bin_kernel(const int* __restrict__ src,
                                                  const int* __restrict__ dst,
                                                  unsigned int* __restrict__ buckets,
                                                  int* __restrict__ gcursor) {
    __shared__ unsigned int staged[CHUNK];          // 16 KB
    __shared__ int hist[NB], scanb[NB], cur[NB], baseb[NB];
    const int tid = threadIdx.x;
    const int base = blockIdx.x * CHUNK;
    int n = N_EDGES - base; if (n > CHUNK) n = CHUNK;

    for (int b = tid; b < NB; b += 256) { hist[b] = 0; cur[b] = 0; }
    __syncthreads();

    // load + histogram (16 edges/thread, coalesced)
    unsigned int v[16];
#pragma unroll
    for (int k = 0; k < 16; ++k) {
        int i = k * 256 + tid;
        if (i < n) {
            int e = base + i;
            unsigned int d = (unsigned int)dst[e];
            v[k] = (d << 16) | (unsigned int)src[e];
            atomicAdd(&hist[d >> 10], 1);
        }
    }
    __syncthreads();
    if (tid == 0) {  // tiny serial scan over 49 bins
        int run = 0;
        for (int b = 0; b < NB; ++b) { scanb[b] = run; run += hist[b]; }
    }
    __syncthreads();
    // LDS scatter into bin-sorted order
#pragma unroll
    for (int k = 0; k < 16; ++k) {
        int i = k * 256 + tid;
        if (i < n) {
            int b = v[k] >> 26;
            int p = scanb[b] + atomicAdd(&cur[b], 1);
            staged[p] = v[k];
        }
    }
    __syncthreads();
    if (tid < NB) baseb[tid] = atomicAdd(&gcursor[tid], hist[tid]);
    __syncthreads();
    // bulk copy runs to global bucket arrays (coalesced within runs)
    for (int i = tid; i < n; i += 256) {
        unsigned int w = staged[i];
        int b = w >> 26;
        buckets[(size_t)b * BCAP + baseb[b] + (i - scanb[b])] = w;
    }
}

// ---------------- CSR build, phase 2: per-bucket local CSR ----------------
// One workgroup per bucket; bucket b covers dst in [b*1024, b*1024+1024).
__global__ __launch_bounds__(1024) void build_csr(const unsigned int* __restrict__ buckets,
                                                  const int* __restrict__ gcursor,
                                                  unsigned int* __restrict__ csr,
                                                  int* __restrict__ off) {
    __shared__ int hist[1024], part[1024], offx[1024], cur[1024];
    __shared__ int s_cnt, s_base;
    const int tid = threadIdx.x;
    const int b = blockIdx.x;

    hist[tid] = 0;
    cur[tid] = 0;
    if (tid == 0) {
        int bs = 0;
        for (int i = 0; i < b; ++i) bs += gcursor[i];
        s_base = bs;
        s_cnt = gcursor[b];
    }
    __syncthreads();
    const int cnt = s_cnt;
    const int gbase = s_base;
    const unsigned int* bk = buckets + (size_t)b * BCAP;

    // pass A: local histogram over 1024 dst slots
    for (int i = tid; i < cnt; i += 1024) {
        unsigned int dl = (bk[i] >> 16) & 1023;
        atomicAdd(&hist[dl], 1);
    }
    __syncthreads();
    // inclusive Hillis-Steele scan over 1024 bins
    part[tid] = hist[tid];
    __syncthreads();
    for (int d = 1; d < 1024; d <<= 1) {
        int t = (tid >= d) ? part[tid - d] : 0;
        __syncthreads();
        part[tid] += t;
        __syncthreads();
    }
    offx[tid] = (tid == 0) ? 0 : part[tid - 1];
    __syncthreads();
    // write global row offsets
    int node = b * 1024 + tid;
    if (node < N_NODES) off[node] = gbase + offx[tid];
    if (b == NB - 1 && tid == 0) off[N_NODES] = gbase + cnt;
    // pass B: place edges (all writes land in this workgroup's csr region)
    for (int i = tid; i < cnt; i += 1024) {
        unsigned int w = bk[i];
        int dl = (w >> 16) & 1023;
        int p = offx[dl] + atomicAdd(&cur[dl], 1);
        csr[gbase + p] = w & 0xFFFFu;   // src
    }
}

// ---------------- dense linears ----------------

__global__ __launch_bounds__(256) void linear64(const float* __restrict__ x,
                                                const float* __restrict__ W,
                                                float* __restrict__ out,
                                                int n_rows) {
    __shared__ float Wt[64 * 65];
    for (int i = threadIdx.x; i < 64 * 64; i += 256) {
        int c = i >> 6, k = i & 63;
        Wt[k * 65 + c] = W[i];
    }
    __syncthreads();
    const int lane = threadIdx.x & 63;
    const int wid  = threadIdx.x >> 6;
    int row0 = blockIdx.x * 64;
    int rend = row0 + 64; if (rend > n_rows) rend = n_rows;
    for (int r = row0 + wid; r < rend; r += 4) {
        float xv = x[(size_t)r * 64 + lane];
        float sum = 0.f;
#pragma unroll
        for (int k = 0; k < 64; ++k) {
            float xk = __shfl(xv, k, 64);
            sum += xk * Wt[k * 65 + lane];
        }
        out[(size_t)r * 64 + lane] = sum;
    }
}

__global__ __launch_bounds__(256) void linear7(const float* __restrict__ x,
                                               const float* __restrict__ W,
                                               float* __restrict__ out,
                                               int n_rows) {
    __shared__ float Ws[7 * 64];
    for (int i = threadIdx.x; i < 7 * 64; i += 256) Ws[i] = W[i];
    __syncthreads();
    const int lane = threadIdx.x & 63;
    const int wid  = threadIdx.x >> 6;
    const int cl   = lane < 7 ? lane : 0;
    int row0 = blockIdx.x * 64;
    int rend = row0 + 64; if (rend > n_rows) rend = n_rows;
    for (int r = row0 + wid; r < rend; r += 4) {
        float xv = x[(size_t)r * 64 + lane];
        float sum = 0.f;
#pragma unroll
        for (int k = 0; k < 64; ++k) {
            float xk = __shfl(xv, k, 64);
            sum += xk * Ws[cl * 64 + k];
        }
        if (lane < 8) out[(size_t)r * 8 + lane] = (lane < 7) ? sum : 0.f;
    }
}

// ---------------- gather aggregation ----------------

__global__ __launch_bounds__(256) void gather64(const int* __restrict__ off,
                                                const unsigned int* __restrict__ csr_src,
                                                const float* __restrict__ t,
                                                const float* __restrict__ b,
                                                float* __restrict__ out,
                                                int do_relu) {
    int node = blockIdx.x * 4 + (threadIdx.x >> 6);
    if (node >= N_NODES) return;
    const int lane = threadIdx.x & 63;
    int e0 = off[node], e1 = off[node + 1];
    float sum = 0.f;
    int e = e0;
    for (; e + 3 < e1; e += 4) {
        unsigned int s0 = csr_src[e];
        unsigned int s1 = csr_src[e + 1];
        unsigned int s2 = csr_src[e + 2];
        unsigned int s3 = csr_src[e + 3];
        float v0 = t[(size_t)s0 * 64 + lane];
        float v1 = t[(size_t)s1 * 64 + lane];
        float v2 = t[(size_t)s2 * 64 + lane];
        float v3 = t[(size_t)s3 * 64 + lane];
        sum += v0 + v1 + v2 + v3;
    }
    for (; e < e1; ++e) sum += t[(size_t)csr_src[e] * 64 + lane];
    float v = sum + b[lane];
    if (do_relu) v = fmaxf(v, 0.f);
    out[(size_t)node * 64 + lane] = v;
}

__global__ __launch_bounds__(256) void gather7(const int* __restrict__ off,
                                               const unsigned int* __restrict__ csr_src,
                                               const float* __restrict__ t3,
                                               const float* __restrict__ b,
                                               float* __restrict__ out) {
    int node = blockIdx.x * 4 + (threadIdx.x >> 6);
    if (node >= N_NODES) return;
    const int lane = threadIdx.x & 63;
    const int sub = lane >> 3;
    const int ch  = lane & 7;
    int e0 = off[node], e1 = off[node + 1];
    float sum = 0.f;
    for (int e = e0 + sub; e < e1; e += 8) {
        sum += t3[(size_t)csr_src[e] * 8 + ch];
    }
    sum += __shfl_xor(sum, 8, 64);
    sum += __shfl_xor(sum, 16, 64);
    sum += __shfl_xor(sum, 32, 64);
    if (lane < 7) out[(size_t)node * 7 + lane] = sum + b[lane];
}

__global__ __launch_bounds__(256) void lsm_inplace(float* __restrict__ out,
                                                   int n_rows) {
    int i = blockIdx.x * 256 + threadIdx.x;
    if (i >= n_rows) return;
    float z[7];
    float m = -1e30f;
#pragma unroll
    for (int c = 0; c < 7; ++c) {
        z[c] = out[i * 7 + c];
        m = fmaxf(m, z[c]);
    }
    float s = 0.f;
#pragma unroll
    for (int c = 0; c < 7; ++c) s += __expf(z[c] - m);
    float l = m + __logf(s);
#pragma unroll
    for (int c = 0; c < 7; ++c) out[i * 7 + c] = z[c] - l;
}

extern "C" void kernel_launch(void* const* d_in, const int* in_sizes, int n_in,
                              void* d_out, int out_size, void* d_ws, size_t ws_size,
                              hipStream_t stream) {
    const float* x  = (const float*)d_in[0];
    const int*   ei = (const int*)d_in[1];
    const float* W1 = (const float*)d_in[2];
    const float* b1 = (const float*)d_in[3];
    const float* W2 = (const float*)d_in[4];
    const float* b2 = (const float*)d_in[5];
    const float* W3 = (const float*)d_in[6];
    const float* b3 = (const float*)d_in[7];
    float* out = (float*)d_out;

    const int* src = ei;
    const int* dst = ei + N_EDGES;

    // workspace layout
    float* A = (float*)d_ws;                       // 50000*64 f32 = 12.8 MB
    float* B = A + (size_t)N_NODES * C;            // 12.8 MB
    unsigned int* csr = (unsigned int*)(B + (size_t)N_NODES * C);  // 1.6M u32
    int* off     = (int*)(csr + N_EDGES);          // 50001
    int* gcursor = off + N_NODES + 8;              // 49
    // phase-1 bucket arrays alias A (8.03 MB <= 12.8 MB, dead after build_csr)
    unsigned int* buckets = (unsigned int*)A;

    const int lingrid = (N_NODES + 63) / 64;
    const int ngrid   = (N_NODES + 3) / 4;

    // ---- CSR build
    hipMemsetAsync(gcursor, 0, NB * sizeof(int), stream);
    bin_kernel<<<(N_EDGES + CHUNK - 1) / CHUNK, 256, 0, stream>>>(src, dst, buckets, gcursor);
    build_csr<<<NB, 1024, 0, stream>>>(buckets, gcursor, csr, off);

    // ---- layer 1 (linear64 overwrites A only after build_csr consumed buckets)
    linear64<<<lingrid, 256, 0, stream>>>(x, W1, A, N_NODES);
    gather64<<<ngrid, 256, 0, stream>>>(off, csr, A, b1, B, 1);

    // ---- layer 2
    linear64<<<lingrid, 256, 0, stream>>>(B, W2, A, N_NODES);
    gather64<<<ngrid, 256, 0, stream>>>(off, csr, A, b2, B, 1);

    // ---- layer 3
    linear7<<<lingrid, 256, 0, stream>>>(B, W3, A, N_NODES);
    gather7<<<ngrid, 256, 0, stream>>>(off, csr, A, b3, out);
    lsm_inplace<<<(N_NODES + 255) / 256, 256, 0, stream>>>(out, N_NODES);
}

// Round 4
// 422.364 us; speedup vs baseline: 2.5421x; 1.0238x over previous
//
#include <hip/hip_runtime.h>
#include <math.h>

#define N_NODES 50000
#define N_EDGES 1600000
#define C 64
#define OUTC 7

#define NB 196         // coarse buckets: dst >> 8  (49999>>8 = 195)
#define BCAP 10240     // bucket capacity (mean 8192, sigma ~90 -> 22 sigma)
#define CHUNK 4096     // edges per phase-1 workgroup

// ---------------- CSR build, phase 1: coarse binning ----------------
// Pack edge as (dst<<16)|src (both < 65536). bucket = v >> 24 (= dst>>8).
__global__ __launch_bounds__(256) void bin_kernel(const int* __restrict__ src,
                                                  const int* __restrict__ dst,
                                                  unsigned int* __restrict__ buckets,
                                                  int* __restrict__ gcursor) {
    __shared__ unsigned int staged[CHUNK];          // 16 KB
    __shared__ int hist[NB], scanb[NB], cur[NB], baseb[NB];
    const int tid = threadIdx.x;
    const int base = blockIdx.x * CHUNK;
    int n = N_EDGES - base; if (n > CHUNK) n = CHUNK;  // always multiple of 4

    for (int b = tid; b < NB; b += 256) { hist[b] = 0; cur[b] = 0; }
    __syncthreads();

    // load 16 edges/thread via int4 (coalesced 16B/lane) + histogram
    const int4* src4 = (const int4*)(src + base);
    const int4* dst4 = (const int4*)(dst + base);
    unsigned int v[16];
    int nv = n >> 2;
#pragma unroll
    for (int k = 0; k < 4; ++k) {
        int i4 = k * 256 + tid;
        if (i4 < nv) {
            int4 s4 = src4[i4];
            int4 d4 = dst4[i4];
            unsigned int d0 = (unsigned int)d4.x, d1 = (unsigned int)d4.y;
            unsigned int d2 = (unsigned int)d4.z, d3 = (unsigned int)d4.w;
            v[k * 4 + 0] = (d0 << 16) | (unsigned int)s4.x;
            v[k * 4 + 1] = (d1 << 16) | (unsigned int)s4.y;
            v[k * 4 + 2] = (d2 << 16) | (unsigned int)s4.z;
            v[k * 4 + 3] = (d3 << 16) | (unsigned int)s4.w;
            atomicAdd(&hist[d0 >> 8], 1);
            atomicAdd(&hist[d1 >> 8], 1);
            atomicAdd(&hist[d2 >> 8], 1);
            atomicAdd(&hist[d3 >> 8], 1);
        }
    }
    __syncthreads();
    if (tid == 0) {  // serial scan over 196 bins (LDS, ~600 cyc)
        int run = 0;
        for (int b = 0; b < NB; ++b) { scanb[b] = run; run += hist[b]; }
    }
    __syncthreads();
    // LDS scatter into bin-sorted order
#pragma unroll
    for (int k = 0; k < 4; ++k) {
        int i4 = k * 256 + tid;
        if (i4 < nv) {
#pragma unroll
            for (int q = 0; q < 4; ++q) {
                unsigned int w = v[k * 4 + q];
                int b = w >> 24;
                int p = scanb[b] + atomicAdd(&cur[b], 1);
                staged[p] = w;
            }
        }
    }
    __syncthreads();
    if (tid < NB) baseb[tid] = atomicAdd(&gcursor[tid], hist[tid]);
    __syncthreads();
    // bulk copy runs to global bucket arrays (coalesced within runs)
    for (int i = tid; i < n; i += 256) {
        unsigned int w = staged[i];
        int b = w >> 24;
        buckets[(size_t)b * BCAP + baseb[b] + (i - scanb[b])] = w;
    }
}

// ---------------- CSR build, phase 2: per-bucket local CSR ----------------
// One 256-thread workgroup per bucket; bucket b covers dst in [b*256, b*256+256).
__global__ __launch_bounds__(256) void build_csr(const unsigned int* __restrict__ buckets,
                                                 const int* __restrict__ gcursor,
                                                 unsigned int* __restrict__ csr,
                                                 int* __restrict__ off) {
    __shared__ int hist[256], part[256], offx[256], cur[256];
    __shared__ int gl[NB];
    __shared__ int s_cnt, s_base;
    const int tid = threadIdx.x;
    const int b = blockIdx.x;

    hist[tid] = 0;
    cur[tid] = 0;
    if (tid < NB) gl[tid] = gcursor[tid];
    __syncthreads();
    if (tid == 0) {
        int bs = 0;
        for (int i = 0; i < b; ++i) bs += gl[i];
        s_base = bs;
        s_cnt = gl[b];
    }
    __syncthreads();
    const int cnt = s_cnt;
    const int gbase = s_base;
    const unsigned int* bk = buckets + (size_t)b * BCAP;

    // pass A: local histogram over 256 dst slots
    for (int i = tid; i < cnt; i += 256) {
        atomicAdd(&hist[(bk[i] >> 16) & 255], 1);
    }
    __syncthreads();
    // inclusive Hillis-Steele scan over 256 bins
    part[tid] = hist[tid];
    __syncthreads();
    for (int d = 1; d < 256; d <<= 1) {
        int t = (tid >= d) ? part[tid - d] : 0;
        __syncthreads();
        part[tid] += t;
        __syncthreads();
    }
    offx[tid] = (tid == 0) ? 0 : part[tid - 1];
    __syncthreads();
    // write global row offsets
    int node = b * 256 + tid;
    if (node < N_NODES) off[node] = gbase + offx[tid];
    if (b == NB - 1 && tid == 0) off[N_NODES] = gbase + cnt;
    // pass B: place edges (all scattered writes land in this wg's csr region)
    for (int i = tid; i < cnt; i += 256) {
        unsigned int w = bk[i];
        int dl = (w >> 16) & 255;
        int p = offx[dl] + atomicAdd(&cur[dl], 1);
        csr[gbase + p] = w & 0xFFFFu;   // src
    }
}

// ---------------- dense linears ----------------

__global__ __launch_bounds__(256) void linear64(const float* __restrict__ x,
                                                const float* __restrict__ W,
                                                float* __restrict__ out,
                                                int n_rows) {
    __shared__ float Wt[64 * 65];  // bank (k+lane)%32: 2-way alias, free
    for (int i = threadIdx.x; i < 64 * 64; i += 256) {
        int c = i >> 6, k = i & 63;
        Wt[k * 65 + c] = W[i];
    }
    __syncthreads();
    const int lane = threadIdx.x & 63;
    const int wid  = threadIdx.x >> 6;
    int row0 = blockIdx.x * 64;
    int rend = row0 + 64; if (rend > n_rows) rend = n_rows;
    for (int r = row0 + wid; r < rend; r += 4) {
        float xv = x[(size_t)r * 64 + lane];
        float sum = 0.f;
#pragma unroll
        for (int k = 0; k < 64; ++k) {
            float xk = __shfl(xv, k, 64);
            sum += xk * Wt[k * 65 + lane];
        }
        out[(size_t)r * 64 + lane] = sum;
    }
}

// out[r*8+c] = sum_k x[r][k]*W3[c][k] (c<7), 0 at c=7
__global__ __launch_bounds__(256) void linear7(const float* __restrict__ x,
                                               const float* __restrict__ W,
                                               float* __restrict__ out,
                                               int n_rows) {
    // Ws2[k*8 + c]: lanes 0..6 hit banks (8k+c)%32 (distinct); lanes 7..63
    // broadcast lane-0's address. Zero conflicts (was 7-way at Ws[c*64+k]).
    __shared__ float Ws2[64 * 8];
    for (int i = threadIdx.x; i < 7 * 64; i += 256) {
        int c = i >> 6, k = i & 63;
        Ws2[k * 8 + c] = W[i];
    }
    __syncthreads();
    const int lane = threadIdx.x & 63;
    const int wid  = threadIdx.x >> 6;
    const int cl   = lane < 7 ? lane : 0;
    int row0 = blockIdx.x * 64;
    int rend = row0 + 64; if (rend > n_rows) rend = n_rows;
    for (int r = row0 + wid; r < rend; r += 4) {
        float xv = x[(size_t)r * 64 + lane];
        float sum = 0.f;
#pragma unroll
        for (int k = 0; k < 64; ++k) {
            float xk = __shfl(xv, k, 64);
            sum += xk * Ws2[k * 8 + cl];
        }
        if (lane < 8) out[(size_t)r * 8 + lane] = (lane < 7) ? sum : 0.f;
    }
}

// ---------------- gather aggregation ----------------

__global__ __launch_bounds__(256) void gather64(const int* __restrict__ off,
                                                const unsigned int* __restrict__ csr_src,
                                                const float* __restrict__ t,
                                                const float* __restrict__ b,
                                                float* __restrict__ out,
                                                int do_relu) {
    int node = blockIdx.x * 4 + (threadIdx.x >> 6);
    if (node >= N_NODES) return;
    const int lane = threadIdx.x & 63;
    int e0 = off[node], e1 = off[node + 1];
    float sum = 0.f;
    int e = e0;
    for (; e + 3 < e1; e += 4) {
        unsigned int s0 = csr_src[e];
        unsigned int s1 = csr_src[e + 1];
        unsigned int s2 = csr_src[e + 2];
        unsigned int s3 = csr_src[e + 3];
        float v0 = t[(size_t)s0 * 64 + lane];
        float v1 = t[(size_t)s1 * 64 + lane];
        float v2 = t[(size_t)s2 * 64 + lane];
        float v3 = t[(size_t)s3 * 64 + lane];
        sum += v0 + v1 + v2 + v3;
    }
    for (; e < e1; ++e) sum += t[(size_t)csr_src[e] * 64 + lane];
    float v = sum + b[lane];
    if (do_relu) v = fmaxf(v, 0.f);
    out[(size_t)node * 64 + lane] = v;
}

// 7-channel gather + bias + log_softmax fused. 8 edge-slots x 8 channel-lanes;
// butterfly over edge slots, then max/logsumexp over the 8-lane channel group.
__global__ __launch_bounds__(256) void gather7_lsm(const int* __restrict__ off,
                                                   const unsigned int* __restrict__ csr_src,
                                                   const float* __restrict__ t3,
                                                   const float* __restrict__ b,
                                                   float* __restrict__ out) {
    int node = blockIdx.x * 4 + (threadIdx.x >> 6);
    if (node >= N_NODES) return;
    const int lane = threadIdx.x & 63;
    const int sub = lane >> 3;  // edge slot 0..7
    const int ch  = lane & 7;   // channel 0..7 (7 = pad)
    int e0 = off[node], e1 = off[node + 1];
    float sum = 0.f;
    for (int e = e0 + sub; e < e1; e += 8) {
        sum += t3[(size_t)csr_src[e] * 8 + ch];
    }
    // reduce across the 8 edge slots (lane bits 3..5)
    sum += __shfl_xor(sum, 8, 64);
    sum += __shfl_xor(sum, 16, 64);
    sum += __shfl_xor(sum, 32, 64);
    // logits: z = sum + bias (pad channel -> -inf)
    float z = (ch < 7) ? (sum + b[ch]) : -1e30f;
    float m = z;
    m = fmaxf(m, __shfl_xor(m, 1, 64));
    m = fmaxf(m, __shfl_xor(m, 2, 64));
    m = fmaxf(m, __shfl_xor(m, 4, 64));
    float ex = (ch < 7) ? __expf(z - m) : 0.f;
    ex += __shfl_xor(ex, 1, 64);
    ex += __shfl_xor(ex, 2, 64);
    ex += __shfl_xor(ex, 4, 64);
    float l = m + __logf(ex);
    if (ch < 7) out[(size_t)node * 7 + ch] = z - l;
}

extern "C" void kernel_launch(void* const* d_in, const int* in_sizes, int n_in,
                              void* d_out, int out_size, void* d_ws, size_t ws_size,
                              hipStream_t stream) {
    const float* x  = (const float*)d_in[0];
    const int*   ei = (const int*)d_in[1];
    const float* W1 = (const float*)d_in[2];
    const float* b1 = (const float*)d_in[3];
    const float* W2 = (const float*)d_in[4];
    const float* b2 = (const float*)d_in[5];
    const float* W3 = (const float*)d_in[6];
    const float* b3 = (const float*)d_in[7];
    float* out = (float*)d_out;

    const int* src = ei;
    const int* dst = ei + N_EDGES;

    // workspace layout
    float* A = (float*)d_ws;                       // 50000*64 f32 = 12.8 MB
    float* B = A + (size_t)N_NODES * C;            // 12.8 MB
    unsigned int* csr = (unsigned int*)(B + (size_t)N_NODES * C);  // 1.6M u32
    int* off     = (int*)(csr + N_EDGES);          // 50001
    int* gcursor = off + N_NODES + 8;              // 196
    // phase-1 bucket arrays alias A (196*10240*4 = 8.03 MB <= 12.8 MB)
    unsigned int* buckets = (unsigned int*)A;

    const int lingrid = (N_NODES + 63) / 64;
    const int ngrid   = (N_NODES + 3) / 4;

    // ---- CSR build
    hipMemsetAsync(gcursor, 0, NB * sizeof(int), stream);
    bin_kernel<<<(N_EDGES + CHUNK - 1) / CHUNK, 256, 0, stream>>>(src, dst, buckets, gcursor);
    build_csr<<<NB, 256, 0, stream>>>(buckets, gcursor, csr, off);

    // ---- layer 1 (linear64 overwrites A only after build_csr consumed buckets)
    linear64<<<lingrid, 256, 0, stream>>>(x, W1, A, N_NODES);
    gather64<<<ngrid, 256, 0, stream>>>(off, csr, A, b1, B, 1);

    // ---- layer 2
    linear64<<<lingrid, 256, 0, stream>>>(B, W2, A, N_NODES);
    gather64<<<ngrid, 256, 0, stream>>>(off, csr, A, b2, B, 1);

    // ---- layer 3 (7 channels padded to stride 8; gather+bias+lsm fused)
    linear7<<<lingrid, 256, 0, stream>>>(B, W3, A, N_NODES);
    gather7_lsm<<<ngrid, 256, 0, stream>>>(off, csr, A, b3, out);
}

// Round 5
// 357.597 us; speedup vs baseline: 3.0025x; 1.1811x over previous
//
#include <hip/hip_runtime.h>
#include <math.h>

#define N_NODES 50000
#define N_EDGES 1600000
#define C 64
#define OUTC 7

#define NB 196         // coarse buckets: dst >> 8  (49999>>8 = 195)
#define BCAP 10240     // bucket capacity (mean 8192, sigma ~90)
#define CHUNK 4096     // edges per phase-1 workgroup

// ---------------- CSR build, phase 1: coarse binning ----------------
// Pack edge as (dst<<16)|src (both < 65536). bucket = v >> 24 (= dst>>8).
__global__ __launch_bounds__(256) void bin_kernel(const int* __restrict__ src,
                                                  const int* __restrict__ dst,
                                                  unsigned int* __restrict__ buckets,
                                                  int* __restrict__ gcursor) {
    __shared__ unsigned int staged[CHUNK];          // 16 KB
    __shared__ int hist[NB], scanb[NB], cur[NB], baseb[NB];
    const int tid = threadIdx.x;
    const int base = blockIdx.x * CHUNK;
    int n = N_EDGES - base; if (n > CHUNK) n = CHUNK;  // multiple of 4

    for (int b = tid; b < NB; b += 256) { hist[b] = 0; cur[b] = 0; }
    __syncthreads();

    const int4* src4 = (const int4*)(src + base);
    const int4* dst4 = (const int4*)(dst + base);
    unsigned int v[16];
    int nv = n >> 2;
#pragma unroll
    for (int k = 0; k < 4; ++k) {
        int i4 = k * 256 + tid;
        if (i4 < nv) {
            int4 s4 = src4[i4];
            int4 d4 = dst4[i4];
            unsigned int d0 = (unsigned int)d4.x, d1 = (unsigned int)d4.y;
            unsigned int d2 = (unsigned int)d4.z, d3 = (unsigned int)d4.w;
            v[k * 4 + 0] = (d0 << 16) | (unsigned int)s4.x;
            v[k * 4 + 1] = (d1 << 16) | (unsigned int)s4.y;
            v[k * 4 + 2] = (d2 << 16) | (unsigned int)s4.z;
            v[k * 4 + 3] = (d3 << 16) | (unsigned int)s4.w;
            atomicAdd(&hist[d0 >> 8], 1);
            atomicAdd(&hist[d1 >> 8], 1);
            atomicAdd(&hist[d2 >> 8], 1);
            atomicAdd(&hist[d3 >> 8], 1);
        }
    }
    __syncthreads();
    if (tid == 0) {
        int run = 0;
        for (int b = 0; b < NB; ++b) { scanb[b] = run; run += hist[b]; }
    }
    __syncthreads();
#pragma unroll
    for (int k = 0; k < 4; ++k) {
        int i4 = k * 256 + tid;
        if (i4 < nv) {
#pragma unroll
            for (int q = 0; q < 4; ++q) {
                unsigned int w = v[k * 4 + q];
                int b = w >> 24;
                int p = scanb[b] + atomicAdd(&cur[b], 1);
                staged[p] = w;
            }
        }
    }
    __syncthreads();
    if (tid < NB) baseb[tid] = atomicAdd(&gcursor[tid], hist[tid]);
    __syncthreads();
    for (int i = tid; i < n; i += 256) {
        unsigned int w = staged[i];
        int b = w >> 24;
        buckets[(size_t)b * BCAP + baseb[b] + (i - scanb[b])] = w;
    }
}

// ---------------- CSR build, phase 2: per-bucket local CSR ----------------
__global__ __launch_bounds__(256) void build_csr(const unsigned int* __restrict__ buckets,
                                                 const int* __restrict__ gcursor,
                                                 unsigned int* __restrict__ csr,
                                                 int* __restrict__ off) {
    __shared__ int hist[256], part[256], offx[256], cur[256];
    __shared__ int gl[NB];
    __shared__ int s_cnt, s_base;
    const int tid = threadIdx.x;
    const int b = blockIdx.x;

    hist[tid] = 0;
    cur[tid] = 0;
    if (tid < NB) gl[tid] = gcursor[tid];
    __syncthreads();
    if (tid == 0) {
        int bs = 0;
        for (int i = 0; i < b; ++i) bs += gl[i];
        s_base = bs;
        s_cnt = gl[b];
    }
    __syncthreads();
    const int cnt = s_cnt;
    const int gbase = s_base;
    const unsigned int* bk = buckets + (size_t)b * BCAP;

    for (int i = tid; i < cnt; i += 256) {
        atomicAdd(&hist[(bk[i] >> 16) & 255], 1);
    }
    __syncthreads();
    part[tid] = hist[tid];
    __syncthreads();
    for (int d = 1; d < 256; d <<= 1) {
        int t = (tid >= d) ? part[tid - d] : 0;
        __syncthreads();
        part[tid] += t;
        __syncthreads();
    }
    offx[tid] = (tid == 0) ? 0 : part[tid - 1];
    __syncthreads();
    int node = b * 256 + tid;
    if (node < N_NODES) off[node] = gbase + offx[tid];
    if (b == NB - 1 && tid == 0) off[N_NODES] = gbase + cnt;
    for (int i = tid; i < cnt; i += 256) {
        unsigned int w = bk[i];
        int dl = (w >> 16) & 255;
        int p = offx[dl] + atomicAdd(&cur[dl], 1);
        csr[gbase + p] = w & 0xFFFFu;
    }
}

// ---------------- dense linears: thread-per-row, zero LDS-pipe ops ----------

// Each thread owns one row: x-row in 64 VGPRs (16 float4; wave working set
// 16 KB -> L1-resident), W indexed by loop counters only -> wave-uniform ->
// scalar/broadcast loads. Inner loop is pure v_fma. No shfl, no ds_*.
__global__ __launch_bounds__(256) void linear64_rows(const float* __restrict__ x,
                                                     const float* __restrict__ W,
                                                     float* __restrict__ out) {
    int r = blockIdx.x * 256 + threadIdx.x;
    if (r >= N_NODES) return;
    float4 xr[16];
    const float4* xp = (const float4*)(x + (size_t)r * 64);
#pragma unroll
    for (int j = 0; j < 16; ++j) xr[j] = xp[j];
    const float* xf = (const float*)xr;

    float4* op = (float4*)(out + (size_t)r * 64);
    for (int c0 = 0; c0 < 64; c0 += 8) {   // dynamic: keeps code size sane
        float acc[8] = {0.f, 0.f, 0.f, 0.f, 0.f, 0.f, 0.f, 0.f};
#pragma unroll
        for (int k = 0; k < 64; ++k) {     // unrolled: xf[k] constant-indexed
            float xv = xf[k];
#pragma unroll
            for (int j = 0; j < 8; ++j)
                acc[j] += xv * W[(c0 + j) * 64 + k];  // uniform address
        }
        op[c0 >> 2]       = make_float4(acc[0], acc[1], acc[2], acc[3]);
        op[(c0 >> 2) + 1] = make_float4(acc[4], acc[5], acc[6], acc[7]);
    }
}

// 7-channel variant; writes stride-8 padded rows (pad channel = 0).
__global__ __launch_bounds__(256) void linear7_rows(const float* __restrict__ x,
                                                    const float* __restrict__ W,
                                                    float* __restrict__ out) {
    int r = blockIdx.x * 256 + threadIdx.x;
    if (r >= N_NODES) return;
    float4 xr[16];
    const float4* xp = (const float4*)(x + (size_t)r * 64);
#pragma unroll
    for (int j = 0; j < 16; ++j) xr[j] = xp[j];
    const float* xf = (const float*)xr;

    float acc[7] = {0.f, 0.f, 0.f, 0.f, 0.f, 0.f, 0.f};
#pragma unroll
    for (int k = 0; k < 64; ++k) {
        float xv = xf[k];
#pragma unroll
        for (int j = 0; j < 7; ++j)
            acc[j] += xv * W[j * 64 + k];  // uniform address
    }
    float4* op = (float4*)(out + (size_t)r * 8);
    op[0] = make_float4(acc[0], acc[1], acc[2], acc[3]);
    op[1] = make_float4(acc[4], acc[5], acc[6], 0.f);
}

// ---------------- gather aggregation ----------------

__global__ __launch_bounds__(256) void gather64(const int* __restrict__ off,
                                                const unsigned int* __restrict__ csr_src,
                                                const float* __restrict__ t,
                                                const float* __restrict__ b,
                                                float* __restrict__ out,
                                                int do_relu) {
    int node = blockIdx.x * 4 + (threadIdx.x >> 6);
    if (node >= N_NODES) return;
    const int lane = threadIdx.x & 63;
    int e0 = off[node], e1 = off[node + 1];
    float sum = 0.f;
    int e = e0;
    for (; e + 3 < e1; e += 4) {
        unsigned int s0 = csr_src[e];
        unsigned int s1 = csr_src[e + 1];
        unsigned int s2 = csr_src[e + 2];
        unsigned int s3 = csr_src[e + 3];
        float v0 = t[(size_t)s0 * 64 + lane];
        float v1 = t[(size_t)s1 * 64 + lane];
        float v2 = t[(size_t)s2 * 64 + lane];
        float v3 = t[(size_t)s3 * 64 + lane];
        sum += v0 + v1 + v2 + v3;
    }
    for (; e < e1; ++e) sum += t[(size_t)csr_src[e] * 64 + lane];
    float v = sum + b[lane];
    if (do_relu) v = fmaxf(v, 0.f);
    out[(size_t)node * 64 + lane] = v;
}

// 7-channel gather + bias + log_softmax fused.
__global__ __launch_bounds__(256) void gather7_lsm(const int* __restrict__ off,
                                                   const unsigned int* __restrict__ csr_src,
                                                   const float* __restrict__ t3,
                                                   const float* __restrict__ b,
                                                   float* __restrict__ out) {
    int node = blockIdx.x * 4 + (threadIdx.x >> 6);
    if (node >= N_NODES) return;
    const int lane = threadIdx.x & 63;
    const int sub = lane >> 3;
    const int ch  = lane & 7;
    int e0 = off[node], e1 = off[node + 1];
    float sum = 0.f;
    for (int e = e0 + sub; e < e1; e += 8) {
        sum += t3[(size_t)csr_src[e] * 8 + ch];
    }
    sum += __shfl_xor(sum, 8, 64);
    sum += __shfl_xor(sum, 16, 64);
    sum += __shfl_xor(sum, 32, 64);
    float z = (ch < 7) ? (sum + b[ch]) : -1e30f;
    float m = z;
    m = fmaxf(m, __shfl_xor(m, 1, 64));
    m = fmaxf(m, __shfl_xor(m, 2, 64));
    m = fmaxf(m, __shfl_xor(m, 4, 64));
    float ex = (ch < 7) ? __expf(z - m) : 0.f;
    ex += __shfl_xor(ex, 1, 64);
    ex += __shfl_xor(ex, 2, 64);
    ex += __shfl_xor(ex, 4, 64);
    float l = m + __logf(ex);
    if (ch < 7) out[(size_t)node * 7 + ch] = z - l;
}

extern "C" void kernel_launch(void* const* d_in, const int* in_sizes, int n_in,
                              void* d_out, int out_size, void* d_ws, size_t ws_size,
                              hipStream_t stream) {
    const float* x  = (const float*)d_in[0];
    const int*   ei = (const int*)d_in[1];
    const float* W1 = (const float*)d_in[2];
    const float* b1 = (const float*)d_in[3];
    const float* W2 = (const float*)d_in[4];
    const float* b2 = (const float*)d_in[5];
    const float* W3 = (const float*)d_in[6];
    const float* b3 = (const float*)d_in[7];
    float* out = (float*)d_out;

    const int* src = ei;
    const int* dst = ei + N_EDGES;

    float* A = (float*)d_ws;                       // 12.8 MB
    float* B = A + (size_t)N_NODES * C;            // 12.8 MB
    unsigned int* csr = (unsigned int*)(B + (size_t)N_NODES * C);
    int* off     = (int*)(csr + N_EDGES);          // 50001
    int* gcursor = off + N_NODES + 8;              // 196
    unsigned int* buckets = (unsigned int*)A;      // aliases A (8.03 MB)

    const int rgrid = (N_NODES + 255) / 256;       // 196
    const int ngrid = (N_NODES + 3) / 4;

    // ---- CSR build
    hipMemsetAsync(gcursor, 0, NB * sizeof(int), stream);
    bin_kernel<<<(N_EDGES + CHUNK - 1) / CHUNK, 256, 0, stream>>>(src, dst, buckets, gcursor);
    build_csr<<<NB, 256, 0, stream>>>(buckets, gcursor, csr, off);

    // ---- layer 1 (A free after build_csr)
    linear64_rows<<<rgrid, 256, 0, stream>>>(x, W1, A);
    gather64<<<ngrid, 256, 0, stream>>>(off, csr, A, b1, B, 1);

    // ---- layer 2
    linear64_rows<<<rgrid, 256, 0, stream>>>(B, W2, A);
    gather64<<<ngrid, 256, 0, stream>>>(off, csr, A, b2, B, 1);

    // ---- layer 3
    linear7_rows<<<rgrid, 256, 0, stream>>>(B, W3, A);
    gather7_lsm<<<ngrid, 256, 0, stream>>>(off, csr, A, b3, out);
}

// Round 6
// 339.382 us; speedup vs baseline: 3.1637x; 1.0537x over previous
//
#include <hip/hip_runtime.h>
#include <math.h>

#define N_NODES 50000
#define N_EDGES 1600000
#define C 64
#define OUTC 7

#define NB 196         // coarse buckets: dst >> 8  (49999>>8 = 195)
#define BCAP 10240     // bucket capacity (mean 8192, sigma ~90)
#define CHUNK 4096     // edges per phase-1 workgroup

// ---------------- CSR build, phase 1: coarse binning ----------------
// Pack edge as (dst<<16)|src (both < 65536). bucket = v >> 24 (= dst>>8).
__global__ __launch_bounds__(256) void bin_kernel(const int* __restrict__ src,
                                                  const int* __restrict__ dst,
                                                  unsigned int* __restrict__ buckets,
                                                  int* __restrict__ gcursor) {
    __shared__ unsigned int staged[CHUNK];          // 16 KB
    __shared__ int hist[NB], scanb[NB], cur[NB], baseb[NB];
    const int tid = threadIdx.x;
    const int base = blockIdx.x * CHUNK;
    int n = N_EDGES - base; if (n > CHUNK) n = CHUNK;  // multiple of 4

    for (int b = tid; b < NB; b += 256) { hist[b] = 0; cur[b] = 0; }
    __syncthreads();

    const int4* src4 = (const int4*)(src + base);
    const int4* dst4 = (const int4*)(dst + base);
    unsigned int v[16];
    int nv = n >> 2;
#pragma unroll
    for (int k = 0; k < 4; ++k) {
        int i4 = k * 256 + tid;
        if (i4 < nv) {
            int4 s4 = src4[i4];
            int4 d4 = dst4[i4];
            unsigned int d0 = (unsigned int)d4.x, d1 = (unsigned int)d4.y;
            unsigned int d2 = (unsigned int)d4.z, d3 = (unsigned int)d4.w;
            v[k * 4 + 0] = (d0 << 16) | (unsigned int)s4.x;
            v[k * 4 + 1] = (d1 << 16) | (unsigned int)s4.y;
            v[k * 4 + 2] = (d2 << 16) | (unsigned int)s4.z;
            v[k * 4 + 3] = (d3 << 16) | (unsigned int)s4.w;
            atomicAdd(&hist[d0 >> 8], 1);
            atomicAdd(&hist[d1 >> 8], 1);
            atomicAdd(&hist[d2 >> 8], 1);
            atomicAdd(&hist[d3 >> 8], 1);
        }
    }
    __syncthreads();
    if (tid == 0) {
        int run = 0;
        for (int b = 0; b < NB; ++b) { scanb[b] = run; run += hist[b]; }
    }
    __syncthreads();
#pragma unroll
    for (int k = 0; k < 4; ++k) {
        int i4 = k * 256 + tid;
        if (i4 < nv) {
#pragma unroll
            for (int q = 0; q < 4; ++q) {
                unsigned int w = v[k * 4 + q];
                int b = w >> 24;
                int p = scanb[b] + atomicAdd(&cur[b], 1);
                staged[p] = w;
            }
        }
    }
    __syncthreads();
    if (tid < NB) baseb[tid] = atomicAdd(&gcursor[tid], hist[tid]);
    __syncthreads();
    for (int i = tid; i < n; i += 256) {
        unsigned int w = staged[i];
        int b = w >> 24;
        buckets[(size_t)b * BCAP + baseb[b] + (i - scanb[b])] = w;
    }
}

// ---------------- CSR build, phase 2: per-bucket local CSR ----------------
__global__ __launch_bounds__(256) void build_csr(const unsigned int* __restrict__ buckets,
                                                 const int* __restrict__ gcursor,
                                                 unsigned int* __restrict__ csr,
                                                 int* __restrict__ off) {
    __shared__ int hist[256], part[256], offx[256], cur[256];
    __shared__ int gl[NB];
    __shared__ int s_cnt, s_base;
    const int tid = threadIdx.x;
    const int b = blockIdx.x;

    hist[tid] = 0;
    cur[tid] = 0;
    if (tid < NB) gl[tid] = gcursor[tid];
    __syncthreads();
    if (tid == 0) {
        int bs = 0;
        for (int i = 0; i < b; ++i) bs += gl[i];
        s_base = bs;
        s_cnt = gl[b];
    }
    __syncthreads();
    const int cnt = s_cnt;
    const int gbase = s_base;
    const unsigned int* bk = buckets + (size_t)b * BCAP;

    for (int i = tid; i < cnt; i += 256) {
        atomicAdd(&hist[(bk[i] >> 16) & 255], 1);
    }
    __syncthreads();
    part[tid] = hist[tid];
    __syncthreads();
    for (int d = 1; d < 256; d <<= 1) {
        int t = (tid >= d) ? part[tid - d] : 0;
        __syncthreads();
        part[tid] += t;
        __syncthreads();
    }
    offx[tid] = (tid == 0) ? 0 : part[tid - 1];
    __syncthreads();
    int node = b * 256 + tid;
    if (node < N_NODES) off[node] = gbase + offx[tid];
    if (b == NB - 1 && tid == 0) off[N_NODES] = gbase + cnt;
    for (int i = tid; i < cnt; i += 256) {
        unsigned int w = bk[i];
        int dl = (w >> 16) & 255;
        int p = offx[dl] + atomicAdd(&cur[dl], 1);
        csr[gbase + p] = w & 0xFFFFu;
    }
}

// ---------------- dense linears: thread-per-row, zero LDS-pipe ops ----------

__global__ __launch_bounds__(128) void linear64_rows(const float* __restrict__ x,
                                                     const float* __restrict__ W,
                                                     float* __restrict__ out) {
    int r = blockIdx.x * 128 + threadIdx.x;
    if (r >= N_NODES) return;
    float4 xr[16];
    const float4* xp = (const float4*)(x + (size_t)r * 64);
#pragma unroll
    for (int j = 0; j < 16; ++j) xr[j] = xp[j];
    const float* xf = (const float*)xr;

    float4* op = (float4*)(out + (size_t)r * 64);
    for (int c0 = 0; c0 < 64; c0 += 8) {
        float acc[8] = {0.f, 0.f, 0.f, 0.f, 0.f, 0.f, 0.f, 0.f};
#pragma unroll
        for (int k = 0; k < 64; ++k) {
            float xv = xf[k];
#pragma unroll
            for (int j = 0; j < 8; ++j)
                acc[j] += xv * W[(c0 + j) * 64 + k];  // uniform address
        }
        op[c0 >> 2]       = make_float4(acc[0], acc[1], acc[2], acc[3]);
        op[(c0 >> 2) + 1] = make_float4(acc[4], acc[5], acc[6], acc[7]);
    }
}

__global__ __launch_bounds__(128) void linear7_rows(const float* __restrict__ x,
                                                    const float* __restrict__ W,
                                                    float* __restrict__ out) {
    int r = blockIdx.x * 128 + threadIdx.x;
    if (r >= N_NODES) return;
    float4 xr[16];
    const float4* xp = (const float4*)(x + (size_t)r * 64);
#pragma unroll
    for (int j = 0; j < 16; ++j) xr[j] = xp[j];
    const float* xf = (const float*)xr;

    float acc[7] = {0.f, 0.f, 0.f, 0.f, 0.f, 0.f, 0.f};
#pragma unroll
    for (int k = 0; k < 64; ++k) {
        float xv = xf[k];
#pragma unroll
        for (int j = 0; j < 7; ++j)
            acc[j] += xv * W[j * 64 + k];  // uniform address
    }
    float4* op = (float4*)(out + (size_t)r * 8);
    op[0] = make_float4(acc[0], acc[1], acc[2], acc[3]);
    op[1] = make_float4(acc[4], acc[5], acc[6], 0.f);
}

// ---------------- gather aggregation (float4-vectorized) ----------------

// Lane map: slot = lane>>4 (4 edge slots), ch4 = lane&15 (4 channels each).
// One dwordx4 load instruction fetches 4 edge rows (1 KB). 8 shfl_xor fold
// the slots; lanes 0..15 write one float4 each.
__global__ __launch_bounds__(256) void gather64(const int* __restrict__ off,
                                                const unsigned int* __restrict__ csr_src,
                                                const float* __restrict__ t,
                                                const float* __restrict__ b,
                                                float* __restrict__ out,
                                                int do_relu) {
    int node = blockIdx.x * 4 + (threadIdx.x >> 6);
    if (node >= N_NODES) return;
    const int lane = threadIdx.x & 63;
    const int slot = lane >> 4;
    const int ch4  = lane & 15;
    int e0 = off[node], e1 = off[node + 1];
    const float4* t4 = (const float4*)t;
    float sx = 0.f, sy = 0.f, sz = 0.f, sw = 0.f;
    for (int e = e0; e < e1; e += 8) {
        int i0 = e + slot;
        int i1 = e + 4 + slot;
        bool p0 = i0 < e1, p1 = i1 < e1;
        unsigned int a0 = csr_src[p0 ? i0 : e];
        unsigned int a1 = csr_src[p1 ? i1 : e];
        float4 v0 = t4[(size_t)a0 * 16 + ch4];
        float4 v1 = t4[(size_t)a1 * 16 + ch4];
        if (p0) { sx += v0.x; sy += v0.y; sz += v0.z; sw += v0.w; }
        if (p1) { sx += v1.x; sy += v1.y; sz += v1.z; sw += v1.w; }
    }
    sx += __shfl_xor(sx, 16, 64); sy += __shfl_xor(sy, 16, 64);
    sz += __shfl_xor(sz, 16, 64); sw += __shfl_xor(sw, 16, 64);
    sx += __shfl_xor(sx, 32, 64); sy += __shfl_xor(sy, 32, 64);
    sz += __shfl_xor(sz, 32, 64); sw += __shfl_xor(sw, 32, 64);
    if (lane < 16) {
        const float4 bb = ((const float4*)b)[ch4];
        float4 r;
        r.x = sx + bb.x; r.y = sy + bb.y; r.z = sz + bb.z; r.w = sw + bb.w;
        if (do_relu) {
            r.x = fmaxf(r.x, 0.f); r.y = fmaxf(r.y, 0.f);
            r.z = fmaxf(r.z, 0.f); r.w = fmaxf(r.w, 0.f);
        }
        ((float4*)(out + (size_t)node * 64))[ch4] = r;
    }
}

// 7-ch gather + bias + log_softmax. Lane map: slot = lane>>1 (32 edge slots),
// h = lane&1 (float4 half of the stride-8 row). One load instr = 32 edges.
__global__ __launch_bounds__(256) void gather7_lsm(const int* __restrict__ off,
                                                   const unsigned int* __restrict__ csr_src,
                                                   const float* __restrict__ t3,
                                                   const float* __restrict__ b,
                                                   float* __restrict__ out) {
    int node = blockIdx.x * 4 + (threadIdx.x >> 6);
    if (node >= N_NODES) return;
    const int lane = threadIdx.x & 63;
    const int slot = lane >> 1;
    const int h    = lane & 1;
    int e0 = off[node], e1 = off[node + 1];
    const float4* t4 = (const float4*)t3;
    float sx = 0.f, sy = 0.f, sz = 0.f, sw = 0.f;
    for (int e = e0 + slot; e < e1; e += 32) {
        unsigned int s = csr_src[e];
        float4 v = t4[(size_t)s * 2 + h];
        sx += v.x; sy += v.y; sz += v.z; sw += v.w;
    }
    // fold 32 slots (lane bits 1..5); bit 0 (h) preserved by xor masks
#pragma unroll
    for (int d = 2; d <= 32; d <<= 1) {
        sx += __shfl_xor(sx, d, 64); sy += __shfl_xor(sy, d, 64);
        sz += __shfl_xor(sz, d, 64); sw += __shfl_xor(sw, d, 64);
    }
    // bias (h==1 channel 3 is pad)
    float z0 = sx + b[h * 4 + 0];
    float z1 = sy + b[h * 4 + 1];
    float z2 = sz + b[h * 4 + 2];
    float z3 = (h == 0) ? (sw + b[3]) : -1e30f;
    float m = fmaxf(fmaxf(z0, z1), fmaxf(z2, z3));
    m = fmaxf(m, __shfl_xor(m, 1, 64));
    float ex = __expf(z0 - m) + __expf(z1 - m) + __expf(z2 - m) + __expf(z3 - m);
    ex += __shfl_xor(ex, 1, 64);
    float l = m + __logf(ex);
    if (lane < 2) {
        float* o = out + (size_t)node * 7 + h * 4;
        o[0] = z0 - l; o[1] = z1 - l; o[2] = z2 - l;
        if (h == 0) o[3] = z3 - l;
    }
}

extern "C" void kernel_launch(void* const* d_in, const int* in_sizes, int n_in,
                              void* d_out, int out_size, void* d_ws, size_t ws_size,
                              hipStream_t stream) {
    const float* x  = (const float*)d_in[0];
    const int*   ei = (const int*)d_in[1];
    const float* W1 = (const float*)d_in[2];
    const float* b1 = (const float*)d_in[3];
    const float* W2 = (const float*)d_in[4];
    const float* b2 = (const float*)d_in[5];
    const float* W3 = (const float*)d_in[6];
    const float* b3 = (const float*)d_in[7];
    float* out = (float*)d_out;

    const int* src = ei;
    const int* dst = ei + N_EDGES;

    float* A = (float*)d_ws;                       // 12.8 MB
    float* B = A + (size_t)N_NODES * C;            // 12.8 MB
    unsigned int* csr = (unsigned int*)(B + (size_t)N_NODES * C);
    int* off     = (int*)(csr + N_EDGES);          // 50001
    int* gcursor = off + N_NODES + 8;              // 196
    unsigned int* buckets = (unsigned int*)A;      // aliases A (8.03 MB)

    const int rgrid = (N_NODES + 127) / 128;       // 391 -> full CU coverage
    const int ngrid = (N_NODES + 3) / 4;

    // ---- CSR build
    hipMemsetAsync(gcursor, 0, NB * sizeof(int), stream);
    bin_kernel<<<(N_EDGES + CHUNK - 1) / CHUNK, 256, 0, stream>>>(src, dst, buckets, gcursor);
    build_csr<<<NB, 256, 0, stream>>>(buckets, gcursor, csr, off);

    // ---- layer 1 (A free after build_csr)
    linear64_rows<<<rgrid, 128, 0, stream>>>(x, W1, A);
    gather64<<<ngrid, 256, 0, stream>>>(off, csr, A, b1, B, 1);

    // ---- layer 2
    linear64_rows<<<rgrid, 128, 0, stream>>>(B, W2, A);
    gather64<<<ngrid, 256, 0, stream>>>(off, csr, A, b2, B, 1);

    // ---- layer 3
    linear7_rows<<<rgrid, 128, 0, stream>>>(B, W3, A);
    gather7_lsm<<<ngrid, 256, 0, stream>>>(off, csr, A, b3, out);
}